// Round 7
// baseline (1659.549 us; speedup 1.0000x reference)
//
#include <hip/hip_runtime.h>

// Problem constants
constexpr int kB  = 1024;
constexpr int kT  = 512;
constexpr int kF  = 32;
constexpr int kE  = 16;
constexpr int kH  = 128;
constexpr int kMB = 16;             // batches per block (MFMA M)
constexpr int kNMB = kB / kMB;      // 64 batch tiles
constexpr int kTc = 32;             // chunk length
constexpr int kNCh = kT / kTc;      // 16 chunks
constexpr size_t kSlots = (size_t)kNMB * kTc * 512;  // gx lane-slots per chunk

typedef __attribute__((ext_vector_type(8))) _Float16 f16x8;
typedef __attribute__((ext_vector_type(4))) float    f32x4;

#define MFMA16(a,b,c) __builtin_amdgcn_mfma_f32_16x16x32_f16(a,b,c,0,0,0)

__device__ __forceinline__ float sigm_hw(float x){
    float e = __builtin_amdgcn_exp2f(-1.442695041f * x);
    return __builtin_amdgcn_rcpf(1.0f + e);
}
__device__ __forceinline__ float tanh_hw(float x){
    float e = __builtin_amdgcn_exp2f(-2.885390082f * x);
    return fmaf(2.0f, __builtin_amdgcn_rcpf(1.0f + e), -1.0f);
}
__device__ __forceinline__ void splitF(float v, _Float16 &hi, _Float16 &lo){
    hi = (_Float16)v;
    lo = (_Float16)(v - (float)hi);
}
__device__ __forceinline__ f16x8 loadW8(const float* __restrict__ p){
    f16x8 r;
#pragma unroll
    for (int j=0;j<8;j++) r[j] = (_Float16)p[j];
    return r;
}
__device__ __forceinline__ unsigned short f2u(_Float16 h){ return __builtin_bit_cast(unsigned short, h); }
__device__ __forceinline__ _Float16 u2f(unsigned short u){ return __builtin_bit_cast(_Float16, u); }
__device__ __forceinline__ unsigned pack2(float a, float b){
    return (unsigned)f2u((_Float16)a) | ((unsigned)f2u((_Float16)b) << 16);
}
// LDS-only barrier: drains ds ops (lgkmcnt) but leaves global loads/stores in
// flight across the barrier (__syncthreads would emit s_waitcnt vmcnt(0) and
// expose full HBM latency every step — that drain was ~80% of round-6's step).
// The compiler still inserts vmcnt waits before USES of prefetched registers,
// and cross-launch buffer ordering is handled by kernel boundaries.
__device__ __forceinline__ void bar_lds(){
    asm volatile("s_waitcnt lgkmcnt(0)\n\ts_barrier" ::: "memory");
}

// LDS: h planes row-major [m][k] (136 = 128+8 pad). Double buffered; one
// lgkm-barrier per step.
struct SRec {
    alignas(16) _Float16 hH[2][16][136];
    alignas(16) _Float16 hL[2][16][136];
    alignas(16) _Float16 xHp[2][16][40];
    alignas(16) _Float16 xLp[2][16][40];
    alignas(16) float hf[16][132];       // head scratch
    alignas(16) float hf2[16][132];
};

// ---------------------------------------------------------------------------
// 128 blocks x 512 threads, 2 roles:
//   blocks  0..63 : layer-0 GRU chunk c, WITH fused gx1 = Wih1@h0_t + bih1
//                   (h0_t is already in this block's A-fragments; iteration it
//                   emits gx slot it-1, loop runs kTc+1 iterations)
//   blocks 64..127: layer-1 GRU chunk c-1 (+head on last chunk)
// In-lane gate update (MFMA C-layout: lane (lq,lm) reg q owns element
// (m=lq*4+q, i=16w+lm) of every gate tile simultaneously).
// ---------------------------------------------------------------------------
__attribute__((amdgpu_waves_per_eu(2, 2)))
__global__ void __launch_bounds__(512) rnn_fused(
    const float* __restrict__ x, const int* __restrict__ tick,
    const float* __restrict__ embed,
    const float* __restrict__ Wih0, const float* __restrict__ Whh0,
    const float* __restrict__ bih0, const float* __restrict__ bhh0,
    const float* __restrict__ Wih1, const float* __restrict__ bih1,
    const float* __restrict__ Whh1, const float* __restrict__ bhh1,
    const float* __restrict__ hw1, const float* __restrict__ hb1,
    const float* __restrict__ hw2, const float* __restrict__ hb2,
    unsigned* __restrict__ gxA, unsigned* __restrict__ gxB,
    float* __restrict__ h0carry, float* __restrict__ h1state,
    float* __restrict__ out, int c)
{
    __shared__ SRec S;
    const int tid = threadIdx.x;
    const int w = tid >> 6, l = tid & 63, lm = l & 15, lq = l >> 4;
    const int i = 16*w + lm;                    // owned gate/hidden column
    const int cls[3] = { i, 128 + i, 256 + i }; // r/z/n weight rows

    if (blockIdx.x < 64) {
        // ========== layer-0 recurrence + fused gx1 GEMM, chunk c ==========
        if (c >= kNCh) return;
        const int mb = blockIdx.x, b0 = mb * kMB;
        unsigned* gA = gxA + (size_t)(c & 1) * kSlots * 4;
        unsigned* gB = gxB + (size_t)(c & 1) * kSlots * 2;

        // persistent weights: Whh0 (48 VGPR) + Wih0 x-part (12) + Wih1 (48)
        f16x8 wv[3][4], xw[3], wg[3][4];
#pragma unroll
        for (int T=0; T<3; T++){
#pragma unroll
            for (int kt=0; kt<4; kt++){
                wv[T][kt] = loadW8(Whh0 + (size_t)cls[T]*kH + kt*32 + lq*8);
                wg[T][kt] = loadW8(Wih1 + (size_t)cls[T]*kH + kt*32 + lq*8);
            }
            xw[T] = loadW8(Wih0 + (size_t)cls[T]*48 + lq*8);
        }
        // acc inits: biases + (emb @ Wih0[:,32:48]) folded per (q, gate)
        float rIni[4], zIni[4], nxIni[4], nhIni;
        const float gIni0 = bih1[cls[0]], gIni1 = bih1[cls[1]], gIni2 = bih1[cls[2]];
        {
            float br = bih0[cls[0]] + bhh0[cls[0]];
            float bz = bih0[cls[1]] + bhh0[cls[1]];
            float bn = bih0[cls[2]];
            nhIni = bhh0[cls[2]];
            const float* w0 = Wih0 + (size_t)cls[0]*48 + 32;
            const float* w1 = Wih0 + (size_t)cls[1]*48 + 32;
            const float* w2 = Wih0 + (size_t)cls[2]*48 + 32;
#pragma unroll
            for (int q=0; q<4; q++){
                const float* ep = embed + (size_t)tick[b0 + lq*4 + q] * kE;
                float s0=0.f, s1=0.f, s2=0.f;
#pragma unroll
                for (int e=0; e<kE; e++){
                    float ev = ep[e];
                    s0 = fmaf(ev, w0[e], s0);
                    s1 = fmaf(ev, w1[e], s1);
                    s2 = fmaf(ev, w2[e], s2);
                }
                rIni[q]=br+s0; zIni[q]=bz+s1; nxIni[q]=bn+s2;
            }
        }
        // state init (ownership covers all 16x128 exactly)
        float hreg[4];
#pragma unroll
        for (int q=0;q<4;q++){
            float h = (c == 0) ? 0.f : h0carry[(size_t)(b0 + lq*4+q)*kH + i];
            hreg[q] = h;
            _Float16 hh,hl; splitF(h,hh,hl);
            S.hH[0][lq*4+q][i]=hh; S.hL[0][lq*4+q][i]=hl;
        }
        // x staging role: thread owns (xm, xk); prefetch 1 step ahead
        const int xm = tid >> 5, xk = tid & 31;
        const size_t xbase = (size_t)(b0+xm)*kT*kF + xk;
        {
            _Float16 a2,b2; splitF(x[xbase + (size_t)(c*kTc)*kF], a2, b2);
            S.xHp[0][xm][xk]=a2; S.xLp[0][xm][xk]=b2;
        }
        int t1 = c*kTc + 1; if (t1 > kT-1) t1 = kT-1;
        float xnext = x[xbase + (size_t)t1*kF];
        bar_lds();

        int buf = 0;
        for (int it=0; it<=kTc; it++){
            f16x8 aHf[4], aLf[4];
#pragma unroll
            for (int kt=0;kt<4;kt++){
                aHf[kt] = *(const f16x8*)&S.hH[buf][lm][kt*32 + lq*8];
                aLf[kt] = *(const f16x8*)&S.hL[buf][lm][kt*32 + lq*8];
            }
            // fused gx1 for step it-1 (A-frags currently hold h0_{it-1})
            if (it >= 1){
                f32x4 gR={gIni0,gIni0,gIni0,gIni0};
                f32x4 gZ={gIni1,gIni1,gIni1,gIni1};
                f32x4 gN={gIni2,gIni2,gIni2,gIni2};
#pragma unroll
                for (int kt=0;kt<4;kt++){
                    gR=MFMA16(aHf[kt],wg[0][kt],gR); gR=MFMA16(aLf[kt],wg[0][kt],gR);
                    gZ=MFMA16(aHf[kt],wg[1][kt],gZ); gZ=MFMA16(aLf[kt],wg[1][kt],gZ);
                    gN=MFMA16(aHf[kt],wg[2][kt],gN); gN=MFMA16(aLf[kt],wg[2][kt],gN);
                }
                const size_t slot = ((size_t)mb*kTc + (it-1))*512 + tid;
                *(uint4*)(gA + slot*4) = make_uint4(pack2(gR[0],gR[1]), pack2(gR[2],gR[3]),
                                                    pack2(gZ[0],gZ[1]), pack2(gZ[2],gZ[3]));
                *(uint2*)(gB + slot*2) = make_uint2(pack2(gN[0],gN[1]), pack2(gN[2],gN[3]));
            }
            if (it < kTc){
                const int nb = buf ^ 1;
                f16x8 xvH = *(const f16x8*)&S.xHp[buf][lm][lq*8];
                f16x8 xvL = *(const f16x8*)&S.xLp[buf][lm][lq*8];
                f32x4 aR ={rIni[0],rIni[1],rIni[2],rIni[3]};
                f32x4 aZ ={zIni[0],zIni[1],zIni[2],zIni[3]};
                f32x4 aNX={nxIni[0],nxIni[1],nxIni[2],nxIni[3]};
                f32x4 aNH={nhIni,nhIni,nhIni,nhIni};
#pragma unroll
                for (int kt=0;kt<4;kt++){
                    aR =MFMA16(aHf[kt],wv[0][kt],aR);  aR =MFMA16(aLf[kt],wv[0][kt],aR);
                    aZ =MFMA16(aHf[kt],wv[1][kt],aZ);  aZ =MFMA16(aLf[kt],wv[1][kt],aZ);
                    aNH=MFMA16(aHf[kt],wv[2][kt],aNH); aNH=MFMA16(aLf[kt],wv[2][kt],aNH);
                }
                aR =MFMA16(xvH,xw[0],aR);  aR =MFMA16(xvL,xw[0],aR);
                aZ =MFMA16(xvH,xw[1],aZ);  aZ =MFMA16(xvL,xw[1],aZ);
                aNX=MFMA16(xvH,xw[2],aNX); aNX=MFMA16(xvL,xw[2],aNX);
                // in-lane gate + state update
#pragma unroll
                for (int q=0;q<4;q++){
                    float r = sigm_hw(aR[q]);
                    float z = sigm_hw(aZ[q]);
                    float n = tanh_hw(fmaf(r, aNH[q], aNX[q]));
                    float h = fmaf(z, hreg[q]-n, n);
                    hreg[q] = h;
                    _Float16 hh,hl; splitF(h,hh,hl);
                    S.hH[nb][lq*4+q][i]=hh;
                    S.hL[nb][lq*4+q][i]=hl;
                }
                { // stage x_{t+1}, prefetch x_{t+2}
                    _Float16 a2,b2; splitF(xnext,a2,b2);
                    S.xHp[nb][xm][xk]=a2; S.xLp[nb][xm][xk]=b2;
                    int tn = c*kTc + it + 2; if (tn > kT-1) tn = kT-1;
                    xnext = x[xbase + (size_t)tn*kF];
                }
                bar_lds();
                buf = nb;
            }
        }
        // carry h to next chunk's l0
#pragma unroll
        for (int q=0;q<4;q++)
            h0carry[(size_t)(b0 + lq*4+q)*kH + i] = hreg[q];
    } else {
        // ================= layer-1 recurrence, chunk e0=c-1 =================
        const int e0 = c - 1;
        if (e0 < 0 || e0 >= kNCh) return;
        const int mb = blockIdx.x - 64, b0 = mb * kMB;
        const unsigned* gA = gxA + (size_t)(e0 & 1) * kSlots * 4;
        const unsigned* gB = gxB + (size_t)(e0 & 1) * kSlots * 2;

        f16x8 wv[3][4];
#pragma unroll
        for (int T=0; T<3; T++)
#pragma unroll
            for (int kt=0; kt<4; kt++)
                wv[T][kt] = loadW8(Whh1 + (size_t)cls[T]*kH + kt*32 + lq*8);
        const float br = bhh1[cls[0]], bz = bhh1[cls[1]], bn = bhh1[cls[2]];

        float hreg[4];
#pragma unroll
        for (int q=0;q<4;q++){
            float h = (e0 == 0) ? 0.f : h1state[(size_t)(b0 + lq*4+q)*kH + i];
            hreg[q]=h;
            _Float16 hh,hl; splitF(h,hh,hl);
            S.hH[0][lq*4+q][i]=hh; S.hL[0][lq*4+q][i]=hl;
        }
        // gx stream straight into registers, prefetched one step ahead
        const size_t base = (size_t)mb*kTc*512 + tid;
        uint4 g4c = *(const uint4*)(gA + base*4);
        uint2 g2c = *(const uint2*)(gB + base*2);
        uint4 g4n = *(const uint4*)(gA + (base + 512)*4);
        uint2 g2n = *(const uint2*)(gB + (base + 512)*2);
        bar_lds();

        int buf = 0;
        for (int tc=0; tc<kTc; tc++){
            const int nb = buf ^ 1;
            f16x8 aHf[4], aLf[4];
#pragma unroll
            for (int kt=0;kt<4;kt++){
                aHf[kt] = *(const f16x8*)&S.hH[buf][lm][kt*32 + lq*8];
                aLf[kt] = *(const f16x8*)&S.hL[buf][lm][kt*32 + lq*8];
            }
            f32x4 aR={br,br,br,br}, aZ={bz,bz,bz,bz}, aNH={bn,bn,bn,bn};
#pragma unroll
            for (int kt=0;kt<4;kt++){
                aR =MFMA16(aHf[kt],wv[0][kt],aR);  aR =MFMA16(aLf[kt],wv[0][kt],aR);
                aZ =MFMA16(aHf[kt],wv[1][kt],aZ);  aZ =MFMA16(aLf[kt],wv[1][kt],aZ);
                aNH=MFMA16(aHf[kt],wv[2][kt],aNH); aNH=MFMA16(aLf[kt],wv[2][kt],aNH);
            }
            const float rx[4] = { (float)u2f((unsigned short)g4c.x), (float)u2f((unsigned short)(g4c.x>>16)),
                                  (float)u2f((unsigned short)g4c.y), (float)u2f((unsigned short)(g4c.y>>16)) };
            const float zx[4] = { (float)u2f((unsigned short)g4c.z), (float)u2f((unsigned short)(g4c.z>>16)),
                                  (float)u2f((unsigned short)g4c.w), (float)u2f((unsigned short)(g4c.w>>16)) };
            const float nx[4] = { (float)u2f((unsigned short)g2c.x), (float)u2f((unsigned short)(g2c.x>>16)),
                                  (float)u2f((unsigned short)g2c.y), (float)u2f((unsigned short)(g2c.y>>16)) };
#pragma unroll
            for (int q=0;q<4;q++){
                float r = sigm_hw(aR[q] + rx[q]);
                float z = sigm_hw(aZ[q] + zx[q]);
                float n = tanh_hw(fmaf(r, aNH[q], nx[q]));
                float h = fmaf(z, hreg[q]-n, n);
                hreg[q] = h;
                _Float16 hh,hl; splitF(h,hh,hl);
                S.hH[nb][lq*4+q][i]=hh;
                S.hL[nb][lq*4+q][i]=hl;
            }
            g4c = g4n; g2c = g2n;
            int tn = tc + 2; if (tn > kTc-1) tn = kTc-1;
            g4n = *(const uint4*)(gA + (base + (size_t)tn*512)*4);
            g2n = *(const uint2*)(gB + (base + (size_t)tn*512)*2);
            bar_lds();
            buf = nb;
        }
#pragma unroll
        for (int q=0;q<4;q++)
            h1state[(size_t)(b0 + lq*4+q)*kH + i] = hreg[q];
        if (e0 == kNCh-1){
            // head: hid = relu(h1 @ hw1^T + hb1); y = hid @ hw2^T + hb2
#pragma unroll
            for (int q=0;q<4;q++) S.hf[lq*4+q][i] = hreg[q];
            __syncthreads();
            const int hm = tid >> 5, i0 = (tid & 31) * 4;
#pragma unroll
            for (int e=0;e<4;e++){
                const float* wr = hw1 + (size_t)(i0+e)*kH;
                float s = hb1[i0+e];
                for (int k2=0;k2<kH;k2++) s = fmaf(wr[k2], S.hf[hm][k2], s);
                S.hf2[hm][i0+e] = fmaxf(s, 0.f);
            }
            __syncthreads();
            if (tid < kMB){
                float s = hb2[0];
                for (int k2=0;k2<kH;k2++) s = fmaf(S.hf2[tid][k2], hw2[k2], s);
                out[b0 + tid] = s;
            }
        }
    }
}

extern "C" void kernel_launch(void* const* d_in, const int* in_sizes, int n_in,
                              void* d_out, int out_size, void* d_ws, size_t ws_size,
                              hipStream_t stream)
{
    const float* x     = (const float*)d_in[0];
    const int*   tick  = (const int*)d_in[1];
    const float* embed = (const float*)d_in[2];
    const float* Wih0  = (const float*)d_in[3];
    const float* Whh0  = (const float*)d_in[4];
    const float* bih0  = (const float*)d_in[5];
    const float* bhh0  = (const float*)d_in[6];
    const float* Wih1  = (const float*)d_in[7];
    const float* Whh1  = (const float*)d_in[8];
    const float* bih1  = (const float*)d_in[9];
    const float* bhh1  = (const float*)d_in[10];
    const float* hw1   = (const float*)d_in[11];
    const float* hb1   = (const float*)d_in[12];
    const float* hw2   = (const float*)d_in[13];
    const float* hb2   = (const float*)d_in[14];
    float* out = (float*)d_out;

    // ws: gxA 2x16.8MB | gxB 2x8.4MB | h0carry 0.5MB | h1state 0.5MB ~ 51.4MB
    unsigned* gxA   = (unsigned*)d_ws;
    unsigned* gxB   = gxA + 2*kSlots*4;
    float*  h0carry = (float*)(gxB + 2*kSlots*2);
    float*  h1state = h0carry + (size_t)kB*kH;

    // 2-stage chunk pipeline: launch c runs l0+gx1(c) and l1(c-1)
    for (int c = 0; c <= kNCh; c++){
        rnn_fused<<<128, 512, 0, stream>>>(x, tick, embed,
            Wih0, Whh0, bih0, bhh0, Wih1, bih1, Whh1, bhh1,
            hw1, hb1, hw2, hb2, gxA, gxB, h0carry, h1state, out, c);
    }
}

// Round 8
// 1221.978 us; speedup vs baseline: 1.3581x; 1.3581x over previous
//
#include <hip/hip_runtime.h>

// Problem constants
constexpr int kB  = 1024;
constexpr int kT  = 512;
constexpr int kF  = 32;
constexpr int kE  = 16;
constexpr int kH  = 128;
constexpr int kMB = 16;             // batches per block (MFMA M)
constexpr int kNMB = kB / kMB;      // 64 batch tiles
constexpr int kTc = 32;             // chunk length
constexpr int kNCh = kT / kTc;      // 16 chunks
constexpr int kTg = kTc / 2;        // t-steps per GEMM block
constexpr size_t kH0Str = (size_t)kB * kTc * kH;     // u32 per h0 chunk buffer
constexpr size_t kSlots = (size_t)kNMB * kTc * 512;  // gx lane-slots per chunk

typedef __attribute__((ext_vector_type(8))) _Float16 f16x8;
typedef __attribute__((ext_vector_type(4))) _Float16 f16x4;
typedef __attribute__((ext_vector_type(4))) float    f32x4;

#define MFMA16(a,b,c) __builtin_amdgcn_mfma_f32_16x16x32_f16(a,b,c,0,0,0)

__device__ __forceinline__ float sigm_hw(float x){
    float e = __builtin_amdgcn_exp2f(-1.442695041f * x);
    return __builtin_amdgcn_rcpf(1.0f + e);
}
__device__ __forceinline__ float tanh_hw(float x){
    float e = __builtin_amdgcn_exp2f(-2.885390082f * x);
    return fmaf(2.0f, __builtin_amdgcn_rcpf(1.0f + e), -1.0f);
}
__device__ __forceinline__ void splitF(float v, _Float16 &hi, _Float16 &lo){
    hi = (_Float16)v;
    lo = (_Float16)(v - (float)hi);
}
__device__ __forceinline__ f16x8 loadW8(const float* __restrict__ p){
    f16x8 r;
#pragma unroll
    for (int j=0;j<8;j++) r[j] = (_Float16)p[j];
    return r;
}
__device__ __forceinline__ unsigned short f2u(_Float16 h){ return __builtin_bit_cast(unsigned short, h); }
__device__ __forceinline__ _Float16 u2f(unsigned short u){ return __builtin_bit_cast(_Float16, u); }
__device__ __forceinline__ unsigned pack2(float a, float b){
    return (unsigned)f2u((_Float16)a) | ((unsigned)f2u((_Float16)b) << 16);
}
// LDS-only barrier: drains ds ops (lgkmcnt) but leaves global loads/stores in
// flight across the barrier. __syncthreads() lowers to
// `s_waitcnt vmcnt(0) lgkmcnt(0); s_barrier`, which drains the h0seq store and
// x/gx prefetch loads (200-900 cyc) EVERY step with only 2 waves/SIMD to hide
// it. The compiler still inserts vmcnt waits before register USES of
// prefetched data (one full step of slack); cross-launch buffer ordering is
// provided by kernel-dispatch boundaries.
__device__ __forceinline__ void bar_lds(){
    asm volatile("s_waitcnt lgkmcnt(0)\n\ts_barrier" ::: "memory");
}

// LDS: h planes row-major [m][k] (136 = 128 + 8 pad). Double buffered; one
// lgkm-barrier per step.
struct SRec {
    alignas(16) _Float16 hH[2][16][136];
    alignas(16) _Float16 hL[2][16][136];
    alignas(16) _Float16 xHp[2][16][40];   // 40 = 32 + 8 pad
    alignas(16) _Float16 xLp[2][16][40];
    alignas(16) float hf[16][132];         // head scratch
    alignas(16) float hf2[16][132];
};
struct SGem {
    alignas(16) _Float16 aH[2][16][136];
    alignas(16) _Float16 aL[2][16][136];
};
union SU { SRec r; SGem g; };

// ---------------------------------------------------------------------------
// 256 blocks x 512 threads, 3 pipeline roles per launch (round-6 structure —
// the only split where every role's weight set fits the 128-VGPR allocation
// the compiler actually grants; round-7's fused l0 needed ~180 and spilled):
//   blocks   0..63 : layer-0 GRU chunk c
//   blocks 64..191 : gx1 GEMM for chunk c-1 (2 blocks per batch tile)
//   blocks 192..255: layer-1 GRU chunk c-2 (+head on last)
// In-lane gate update via MFMA C-layout: lane (lq,lm) reg q owns element
// (m=lq*4+q, i=16w+lm) of every gate tile simultaneously.
// ---------------------------------------------------------------------------
__attribute__((amdgpu_waves_per_eu(2, 2)))
__global__ void __launch_bounds__(512) rnn_fused(
    const float* __restrict__ x, const int* __restrict__ tick,
    const float* __restrict__ embed,
    const float* __restrict__ Wih0, const float* __restrict__ Whh0,
    const float* __restrict__ bih0, const float* __restrict__ bhh0,
    const float* __restrict__ Wih1, const float* __restrict__ bih1,
    const float* __restrict__ Whh1, const float* __restrict__ bhh1,
    const float* __restrict__ hw1, const float* __restrict__ hb1,
    const float* __restrict__ hw2, const float* __restrict__ hb2,
    unsigned* __restrict__ h0seq, unsigned* __restrict__ gxA,
    unsigned* __restrict__ gxB, float* __restrict__ h1state,
    float* __restrict__ out, int c)
{
    __shared__ SU sm;
    const int tid = threadIdx.x;
    const int w = tid >> 6, l = tid & 63, lm = l & 15, lq = l >> 4;
    const int i = 16*w + lm;                    // owned gate/hidden column
    const int cls[3] = { i, 128 + i, 256 + i }; // r/z/n weight rows

    if (blockIdx.x < 64) {
        // ================= layer-0 recurrence, chunk c =================
        if (c >= kNCh) return;
        SRec &S = sm.r;
        const int mb = blockIdx.x, b0 = mb * kMB;
        unsigned* h0w = h0seq + (size_t)(c & 1) * kH0Str;

        f16x8 wv[3][4], xw[3];
#pragma unroll
        for (int T=0; T<3; T++){
#pragma unroll
            for (int kt=0; kt<4; kt++)
                wv[T][kt] = loadW8(Whh0 + (size_t)cls[T]*kH + kt*32 + lq*8);
            xw[T] = loadW8(Wih0 + (size_t)cls[T]*48 + lq*8);
        }
        // acc inits: biases + (emb @ Wih0[:,32:48]) folded per (q, gate)
        float rIni[4], zIni[4], nxIni[4], nhIni;
        {
            float br = bih0[cls[0]] + bhh0[cls[0]];
            float bz = bih0[cls[1]] + bhh0[cls[1]];
            float bn = bih0[cls[2]];
            nhIni = bhh0[cls[2]];
            const float* w0 = Wih0 + (size_t)cls[0]*48 + 32;
            const float* w1 = Wih0 + (size_t)cls[1]*48 + 32;
            const float* w2 = Wih0 + (size_t)cls[2]*48 + 32;
#pragma unroll
            for (int q=0; q<4; q++){
                const float* ep = embed + (size_t)tick[b0 + lq*4 + q] * kE;
                float s0=0.f, s1=0.f, s2=0.f;
#pragma unroll
                for (int e=0; e<kE; e++){
                    float ev = ep[e];
                    s0 = fmaf(ev, w0[e], s0);
                    s1 = fmaf(ev, w1[e], s1);
                    s2 = fmaf(ev, w2[e], s2);
                }
                rIni[q]=br+s0; zIni[q]=bz+s1; nxIni[q]=bn+s2;
            }
        }
        // state init via ownership (covers all 16x128 exactly)
        float hreg[4];
        if (c == 0){
#pragma unroll
            for (int q=0;q<4;q++){
                hreg[q]=0.f;
                S.hH[0][lq*4+q][i]=(_Float16)0.f;
                S.hL[0][lq*4+q][i]=(_Float16)0.f;
            }
        } else {
            const unsigned* h0p = h0seq + (size_t)((c-1) & 1) * kH0Str;
#pragma unroll
            for (int q=0;q<4;q++){
                unsigned u = h0p[((size_t)(mb*kTc + kTc-1)*16 + lq*4+q)*kH + i];
                _Float16 hh = u2f((unsigned short)(u>>16)), hl = u2f((unsigned short)u);
                hreg[q] = (float)hh + (float)hl;
                S.hH[0][lq*4+q][i]=hh; S.hL[0][lq*4+q][i]=hl;
            }
        }
        // x staging role: thread owns (xm, xk); prefetch 1 step ahead
        const int xm = tid >> 5, xk = tid & 31;
        const size_t xbase = (size_t)(b0+xm)*kT*kF + xk;
        {
            _Float16 a2,b2; splitF(x[xbase + (size_t)(c*kTc)*kF], a2, b2);
            S.xHp[0][xm][xk]=a2; S.xLp[0][xm][xk]=b2;
        }
        int t1 = c*kTc + 1; if (t1 > kT-1) t1 = kT-1;
        float xnext = x[xbase + (size_t)t1*kF];
        bar_lds();

        int buf = 0;
        for (int tc=0; tc<kTc; tc++){
            const int nb = buf ^ 1;
            f16x8 aHf[4], aLf[4];
#pragma unroll
            for (int kt=0;kt<4;kt++){
                aHf[kt] = *(const f16x8*)&S.hH[buf][lm][kt*32 + lq*8];
                aLf[kt] = *(const f16x8*)&S.hL[buf][lm][kt*32 + lq*8];
            }
            f16x8 xvH = *(const f16x8*)&S.xHp[buf][lm][lq*8];
            f16x8 xvL = *(const f16x8*)&S.xLp[buf][lm][lq*8];
            f32x4 aR ={rIni[0],rIni[1],rIni[2],rIni[3]};
            f32x4 aZ ={zIni[0],zIni[1],zIni[2],zIni[3]};
            f32x4 aNX={nxIni[0],nxIni[1],nxIni[2],nxIni[3]};
            f32x4 aNH={nhIni,nhIni,nhIni,nhIni};
#pragma unroll
            for (int kt=0;kt<4;kt++){
                aR =MFMA16(aHf[kt],wv[0][kt],aR);  aR =MFMA16(aLf[kt],wv[0][kt],aR);
                aZ =MFMA16(aHf[kt],wv[1][kt],aZ);  aZ =MFMA16(aLf[kt],wv[1][kt],aZ);
                aNH=MFMA16(aHf[kt],wv[2][kt],aNH); aNH=MFMA16(aLf[kt],wv[2][kt],aNH);
            }
            aR =MFMA16(xvH,xw[0],aR);  aR =MFMA16(xvL,xw[0],aR);
            aZ =MFMA16(xvH,xw[1],aZ);  aZ =MFMA16(xvL,xw[1],aZ);
            aNX=MFMA16(xvH,xw[2],aNX); aNX=MFMA16(xvL,xw[2],aNX);
            // in-lane gate + state update (MFMA C regs stay local)
            unsigned pk[4];
#pragma unroll
            for (int q=0;q<4;q++){
                float r = sigm_hw(aR[q]);
                float z = sigm_hw(aZ[q]);
                float n = tanh_hw(fmaf(r, aNH[q], aNX[q]));
                float h = fmaf(z, hreg[q]-n, n);
                hreg[q] = h;
                _Float16 hh,hl; splitF(h,hh,hl);
                S.hH[nb][lq*4+q][i]=hh;
                S.hL[nb][lq*4+q][i]=hl;
                pk[q] = ((unsigned)f2u(hh)<<16) | f2u(hl);
            }
#pragma unroll
            for (int q=0;q<4;q++)
                h0w[((size_t)(mb*kTc + tc)*16 + lq*4+q)*kH + i] = pk[q];
            { // stage x_{t+1}, prefetch x_{t+2}
                _Float16 a2,b2; splitF(xnext,a2,b2);
                S.xHp[nb][xm][xk]=a2; S.xLp[nb][xm][xk]=b2;
                int tn = c*kTc + tc + 2; if (tn > kT-1) tn = kT-1;
                xnext = x[xbase + (size_t)tn*kF];
            }
            bar_lds();
            buf = nb;
        }
    } else if (blockIdx.x < 192) {
        // ============ gx1 GEMM for chunk g=c-1 (non-recurrent) ============
        const int g = c - 1;
        if (g < 0 || g >= kNCh) return;
        SGem &S = sm.g;
        const int bid = blockIdx.x - 64;
        const int mb = bid >> 1, t0 = (bid & 1) * kTg;
        const unsigned* h0r = h0seq + (size_t)(g & 1) * kH0Str;
        unsigned* gA = gxA + (size_t)(g & 1) * kSlots * 4;
        unsigned* gB = gxB + (size_t)(g & 1) * kSlots * 2;

        f16x8 wv[3][4]; float bI[3];
#pragma unroll
        for (int T=0; T<3; T++){
#pragma unroll
            for (int kt=0; kt<4; kt++)
                wv[T][kt] = loadW8(Wih1 + (size_t)cls[T]*kH + kt*32 + lq*8);
            bI[T] = bih1[cls[T]];
        }
        const int sr = tid >> 5, sq = tid & 31;   // staging role: row, u32-quad
        auto ld = [&](int t){
            return *(const uint4*)(h0r + ((size_t)(mb*kTc + t)*16 + sr)*kH + 4*sq);
        };
        auto stage = [&](int bf, uint4 u){
            f16x4 vh = { u2f((unsigned short)(u.x>>16)), u2f((unsigned short)(u.y>>16)),
                         u2f((unsigned short)(u.z>>16)), u2f((unsigned short)(u.w>>16)) };
            f16x4 vl = { u2f((unsigned short)u.x), u2f((unsigned short)u.y),
                         u2f((unsigned short)u.z), u2f((unsigned short)u.w) };
            *(f16x4*)&S.aH[bf][sr][4*sq] = vh;
            *(f16x4*)&S.aL[bf][sr][4*sq] = vl;
        };
        stage(0, ld(t0));
        uint4 nxt = ld(t0 + 1);
        bar_lds();
        for (int tt=0; tt<kTg; tt++){
            const int t = t0 + tt, bf = tt & 1;
            f16x8 fH[4], fL[4];
#pragma unroll
            for (int kt=0;kt<4;kt++){
                fH[kt] = *(const f16x8*)&S.aH[bf][lm][kt*32 + lq*8];
                fL[kt] = *(const f16x8*)&S.aL[bf][lm][kt*32 + lq*8];
            }
            if (tt+1 < kTg) stage(bf^1, nxt);
            if (tt+2 < kTg) nxt = ld(t0 + tt + 2);
            f32x4 aR = {bI[0],bI[0],bI[0],bI[0]};
            f32x4 aZ = {bI[1],bI[1],bI[1],bI[1]};
            f32x4 aN = {bI[2],bI[2],bI[2],bI[2]};
#pragma unroll
            for (int kt=0;kt<4;kt++){
                aR=MFMA16(fH[kt],wv[0][kt],aR); aR=MFMA16(fL[kt],wv[0][kt],aR);
                aZ=MFMA16(fH[kt],wv[1][kt],aZ); aZ=MFMA16(fL[kt],wv[1][kt],aZ);
                aN=MFMA16(fH[kt],wv[2][kt],aN); aN=MFMA16(fL[kt],wv[2][kt],aN);
            }
            // store per-consumer-lane packed: l1 lane tid reads exactly this
            const size_t slot = ((size_t)mb*kTc + t)*512 + tid;
            *(uint4*)(gA + slot*4) = make_uint4(pack2(aR[0],aR[1]), pack2(aR[2],aR[3]),
                                                pack2(aZ[0],aZ[1]), pack2(aZ[2],aZ[3]));
            *(uint2*)(gB + slot*2) = make_uint2(pack2(aN[0],aN[1]), pack2(aN[2],aN[3]));
            bar_lds();
        }
    } else {
        // ================= layer-1 recurrence, chunk e0=c-2 =================
        const int e0 = c - 2;
        if (e0 < 0 || e0 >= kNCh) return;
        SRec &S = sm.r;
        const int mb = blockIdx.x - 192, b0 = mb * kMB;
        const unsigned* gA = gxA + (size_t)(e0 & 1) * kSlots * 4;
        const unsigned* gB = gxB + (size_t)(e0 & 1) * kSlots * 2;

        f16x8 wv[3][4];
#pragma unroll
        for (int T=0; T<3; T++)
#pragma unroll
            for (int kt=0; kt<4; kt++)
                wv[T][kt] = loadW8(Whh1 + (size_t)cls[T]*kH + kt*32 + lq*8);
        const float br = bhh1[cls[0]], bz = bhh1[cls[1]], bn = bhh1[cls[2]];

        float hreg[4];
        if (e0 == 0){
#pragma unroll
            for (int q=0;q<4;q++){
                hreg[q]=0.f;
                S.hH[0][lq*4+q][i]=(_Float16)0.f;
                S.hL[0][lq*4+q][i]=(_Float16)0.f;
            }
        } else {
#pragma unroll
            for (int q=0;q<4;q++){
                float h = h1state[(size_t)(b0 + lq*4+q)*kH + i];
                hreg[q]=h;
                _Float16 hh,hl; splitF(h,hh,hl);
                S.hH[0][lq*4+q][i]=hh; S.hL[0][lq*4+q][i]=hl;
            }
        }
        // gx stream straight into registers, prefetched one step ahead
        const size_t base = (size_t)mb*kTc*512 + tid;
        uint4 g4c = *(const uint4*)(gA + base*4);
        uint2 g2c = *(const uint2*)(gB + base*2);
        uint4 g4n = *(const uint4*)(gA + (base + 512)*4);
        uint2 g2n = *(const uint2*)(gB + (base + 512)*2);
        bar_lds();

        int buf = 0;
        for (int tc=0; tc<kTc; tc++){
            const int nb = buf ^ 1;
            f16x8 aHf[4], aLf[4];
#pragma unroll
            for (int kt=0;kt<4;kt++){
                aHf[kt] = *(const f16x8*)&S.hH[buf][lm][kt*32 + lq*8];
                aLf[kt] = *(const f16x8*)&S.hL[buf][lm][kt*32 + lq*8];
            }
            f32x4 aR={br,br,br,br}, aZ={bz,bz,bz,bz}, aNH={bn,bn,bn,bn};
#pragma unroll
            for (int kt=0;kt<4;kt++){
                aR =MFMA16(aHf[kt],wv[0][kt],aR);  aR =MFMA16(aLf[kt],wv[0][kt],aR);
                aZ =MFMA16(aHf[kt],wv[1][kt],aZ);  aZ =MFMA16(aLf[kt],wv[1][kt],aZ);
                aNH=MFMA16(aHf[kt],wv[2][kt],aNH); aNH=MFMA16(aLf[kt],wv[2][kt],aNH);
            }
            const float rx[4] = { (float)u2f((unsigned short)g4c.x), (float)u2f((unsigned short)(g4c.x>>16)),
                                  (float)u2f((unsigned short)g4c.y), (float)u2f((unsigned short)(g4c.y>>16)) };
            const float zx[4] = { (float)u2f((unsigned short)g4c.z), (float)u2f((unsigned short)(g4c.z>>16)),
                                  (float)u2f((unsigned short)g4c.w), (float)u2f((unsigned short)(g4c.w>>16)) };
            const float nx[4] = { (float)u2f((unsigned short)g2c.x), (float)u2f((unsigned short)(g2c.x>>16)),
                                  (float)u2f((unsigned short)g2c.y), (float)u2f((unsigned short)(g2c.y>>16)) };
#pragma unroll
            for (int q=0;q<4;q++){
                float r = sigm_hw(aR[q] + rx[q]);
                float z = sigm_hw(aZ[q] + zx[q]);
                float n = tanh_hw(fmaf(r, aNH[q], nx[q]));
                float h = fmaf(z, hreg[q]-n, n);
                hreg[q] = h;
                _Float16 hh,hl; splitF(h,hh,hl);
                S.hH[nb][lq*4+q][i]=hh;
                S.hL[nb][lq*4+q][i]=hl;
            }
            g4c = g4n; g2c = g2n;
            int tn = tc + 2; if (tn > kTc-1) tn = kTc-1;
            g4n = *(const uint4*)(gA + (base + (size_t)tn*512)*4);
            g2n = *(const uint2*)(gB + (base + (size_t)tn*512)*2);
            bar_lds();
            buf = nb;
        }
#pragma unroll
        for (int q=0;q<4;q++)
            h1state[(size_t)(b0 + lq*4+q)*kH + i] = hreg[q];
        if (e0 == kNCh-1){
            // head: hid = relu(h1 @ hw1^T + hb1); y = hid @ hw2^T + hb2
#pragma unroll
            for (int q=0;q<4;q++) S.hf[lq*4+q][i] = hreg[q];
            __syncthreads();
            const int hm = tid >> 5, i0 = (tid & 31) * 4;
#pragma unroll
            for (int e=0;e<4;e++){
                const float* wr = hw1 + (size_t)(i0+e)*kH;
                float s = hb1[i0+e];
                for (int k2=0;k2<kH;k2++) s = fmaf(wr[k2], S.hf[hm][k2], s);
                S.hf2[hm][i0+e] = fmaxf(s, 0.f);
            }
            __syncthreads();
            if (tid < kMB){
                float s = hb2[0];
                for (int k2=0;k2<kH;k2++) s = fmaf(S.hf2[tid][k2], hw2[k2], s);
                out[b0 + tid] = s;
            }
        }
    }
}

extern "C" void kernel_launch(void* const* d_in, const int* in_sizes, int n_in,
                              void* d_out, int out_size, void* d_ws, size_t ws_size,
                              hipStream_t stream)
{
    const float* x     = (const float*)d_in[0];
    const int*   tick  = (const int*)d_in[1];
    const float* embed = (const float*)d_in[2];
    const float* Wih0  = (const float*)d_in[3];
    const float* Whh0  = (const float*)d_in[4];
    const float* bih0  = (const float*)d_in[5];
    const float* bhh0  = (const float*)d_in[6];
    const float* Wih1  = (const float*)d_in[7];
    const float* Whh1  = (const float*)d_in[8];
    const float* bih1  = (const float*)d_in[9];
    const float* bhh1  = (const float*)d_in[10];
    const float* hw1   = (const float*)d_in[11];
    const float* hb1   = (const float*)d_in[12];
    const float* hw2   = (const float*)d_in[13];
    const float* hb2   = (const float*)d_in[14];
    float* out = (float*)d_out;

    // ws: h0seq 2x16.8MB | gxA 2x16.8MB | gxB 2x8.4MB | h1state 0.5MB ~ 84.5MB
    unsigned* h0seq = (unsigned*)d_ws;
    unsigned* gxA   = h0seq + 2*kH0Str;
    unsigned* gxB   = gxA + 2*kSlots*4;
    float*  h1state = (float*)(gxB + 2*kSlots*2);

    for (int c = 0; c <= kNCh + 1; c++){
        rnn_fused<<<256, 512, 0, stream>>>(x, tick, embed,
            Wih0, Whh0, bih0, bhh0, Wih1, bih1, Whh1, bhh1,
            hw1, hb1, hw2, hb2, h0seq, gxA, gxB, h1state, out, c);
    }
}